// Round 1
// baseline (443.844 us; speedup 1.0000x reference)
//
#include <hip/hip_runtime.h>
#include <hip/hip_cooperative_groups.h>

namespace cg = cooperative_groups;

// Problem constants (from reference setup_inputs): B=8, C=3, H=W=512
#define HW     262144        // 512*512
#define HW4    65536         // HW/4 float4 elements per channel
#define BC     24            // B*C channels
#define NB     256           // bins
#define NTOT   6291456       // B*C*H*W

#define GPC    42            // blocks per channel
#define NBLK   (BC * GPC)    // 1008 blocks total (<= 256 CU * 4 blocks/CU)
#define STRIDE (GPC * 256)   // 10752 float4 stride within channel
#define NIT    7             // ceil(HW4 / STRIDE)

// Workspace layout (bytes), nothing pre-zeroed:
//   hsPart : int[NBLK][256]
//   hrPart : int[NBLK][256]
//   lut    : float[24][256]
//   lsum   : float[NBLK]
#define WS_HSP_OFF  0
#define WS_HRP_OFF  (NBLK * NB * 4)                       // 1,032,192
#define WS_LUT_OFF  (2 * NBLK * NB * 4)                   // 2,064,384
#define WS_LSUM_OFF (2 * NBLK * NB * 4 + BC * NB * 4)     // 2,088,960

__device__ __forceinline__ int quantize(float x, float m) {
    // jnp.clip(jnp.round((x+1)*0.5*255 * m), 0, 255)
    float v = (x + 1.0f) * 0.5f * 255.0f * m;
    float r = rintf(v);
    r = fminf(fmaxf(r, 0.0f), 255.0f);
    return (int)r;
}

__device__ __forceinline__ int incl_scan256(int v, int t, int* buf) {
    buf[t] = v;
    __syncthreads();
#pragma unroll
    for (int off = 1; off < NB; off <<= 1) {
        int x = (t >= off) ? buf[t - off] : 0;
        __syncthreads();
        buf[t] += x;
        __syncthreads();
    }
    return buf[t];
}

// Single cooperative kernel: hist -> (grid sync) -> lut -> (grid sync)
// -> loss -> (grid sync) -> final reduce.
// Quantized ref bins + mask bits retained in registers between phase 1 and
// phase 3 so ref/ms are read exactly once from HBM.
__global__ void __launch_bounds__(256, 4)
fused_kernel(const float4* __restrict__ inp4,
             const float4* __restrict__ tar4,
             const float4* __restrict__ ref4,
             const float4* __restrict__ ms4,
             const float4* __restrict__ mt4,
             int* __restrict__ hsPart, int* __restrict__ hrPart,
             float* __restrict__ lut, float* __restrict__ lsum,
             float* __restrict__ out) {
    cg::grid_group grid = cg::this_grid();

    __shared__ int   wh[4 * 2 * NB];     // wave-private [wave][s/r][bin]
    __shared__ int   buf[NB];
    __shared__ float xp[NB];
    __shared__ float fp[NB];
    __shared__ float llut[NB];
    __shared__ float wsum[4];
    __shared__ int firstS, firstR, nOccS, nOccR;

    const int t    = threadIdx.x;
    const int wave = t >> 6;
    const int lane = t & 63;
    const int cb   = blockIdx.x;      // 0..NBLK-1
    const int c    = cb / GPC;        // channel 0..23
    const int g    = cb % GPC;        // slice within channel
    const int b    = c / 3;

#pragma unroll
    for (int j = 0; j < 8; ++j) wh[t + j * 256] = 0;
    __syncthreads();

    const float4* refc = ref4 + (size_t)c * HW4;
    const float4* tarc = tar4 + (size_t)c * HW4;
    const float4* msb  = ms4 + (size_t)b * HW4;
    const float4* mtb  = mt4 + (size_t)b * HW4;

    int* whS = &wh[wave * 512];
    int* whR = &wh[wave * 512 + 256];

    const int base0 = g * 256 + t;    // i = base0 + j*STRIDE, guarded by HW4

    unsigned qp[NIT];                 // 4 x 8-bit quantized ref bins per iter
    unsigned mbv = 0;                 // 4 mask bits per iter (28 bits used)
    int n0s = 0, n0r = 0;             // masked-out pixels counted in registers

    // ---------------- Phase 1: histograms (ref/ms + tar/mt read once) ------
#pragma unroll
    for (int j = 0; j < NIT; ++j) {
        const int i = base0 + j * STRIDE;
        qp[j] = 0u;
        if (i < HW4) {
            const float4 R  = refc[i];
            const float4 M  = msb[i];
            const float4 T  = tarc[i];
            const float4 MT = mtb[i];
            const float rv[4]  = {R.x, R.y, R.z, R.w};
            const float mv[4]  = {M.x, M.y, M.z, M.w};
            const float tv[4]  = {T.x, T.y, T.z, T.w};
            const float mtv[4] = {MT.x, MT.y, MT.z, MT.w};
            unsigned q4 = 0;
#pragma unroll
            for (int k = 0; k < 4; ++k) {
                const int qs = quantize(rv[k], mv[k]);   // 0 when mask==0
                q4 |= ((unsigned)qs) << (8 * k);
                if (mv[k] != 0.0f) { atomicAdd(&whS[qs], 1); mbv |= 1u << (4 * j + k); }
                else n0s++;
                if (mtv[k] != 0.0f) atomicAdd(&whR[quantize(tv[k], mtv[k])], 1);
                else n0r++;
            }
            qp[j] = q4;
        }
    }
    // fold register bin-0 counts: wave-reduce, one LDS add per wave
#pragma unroll
    for (int off = 32; off > 0; off >>= 1) {
        n0s += __shfl_down(n0s, off);
        n0r += __shfl_down(n0r, off);
    }
    if (lane == 0) {
        if (n0s) atomicAdd(&whS[0], n0s);
        if (n0r) atomicAdd(&whR[0], n0r);
    }
    __syncthreads();

    // merge 4 wave-hists -> per-block partial, plain coalesced store
    const int hs = wh[t] + wh[512 + t] + wh[1024 + t] + wh[1536 + t];
    const int hr = wh[256 + t] + wh[768 + t] + wh[1280 + t] + wh[1792 + t];
    hsPart[cb * NB + t] = hs;
    hrPart[cb * NB + t] = hr;

    grid.sync();

    // ---------------- Phase 2: LUT (blocks 0..23, one per channel) ---------
    if (cb < BC) {
        int cs = 0, cr = 0;
#pragma unroll 6
        for (int gg = 0; gg < GPC; ++gg) {
            cs += hsPart[(cb * GPC + gg) * NB + t];
            cr += hrPart[(cb * GPC + gg) * NB + t];
        }

        if (t == 0) { firstS = NB; firstR = NB; nOccS = 0; nOccR = 0; }
        __syncthreads();
        if (cs > 0) { atomicMin(&firstS, t); atomicAdd(&nOccS, 1); }
        if (cr > 0) { atomicMin(&firstR, t); atomicAdd(&nOccR, 1); }
        __syncthreads();

        const int csz = (t == firstS) ? 0 : cs;
        const int crz = (t == firstR) ? 0 : cr;

        const int cumS = incl_scan256(csz, t, buf);
        const int totS = buf[NB - 1];
        __syncthreads();
        const int cumR = incl_scan256(crz, t, buf);
        const int totR = buf[NB - 1];
        __syncthreads();
        const int occ2 = (cr > 0 && t != firstR) ? 1 : 0;
        const int rank = incl_scan256(occ2, t, buf) - occ2;  // exclusive
        __syncthreads();

        const float x  = (float)cumS / fmaxf((float)totS, 1.0f);
        const float rq = (float)cumR / fmaxf((float)totR, 1.0f);

        xp[t] = 2.0f;
        fp[t] = 0.0f;
        __syncthreads();
        if (occ2) { xp[rank] = rq; fp[rank] = (float)t; }
        __syncthreads();

        // jnp.interp semantics: searchsorted-right, i clipped to [1,255]
        int lo = 0, hi = NB;
        while (lo < hi) {
            int mid = (lo + hi) >> 1;
            if (xp[mid] > x) hi = mid; else lo = mid + 1;
        }
        int i2 = lo;
        i2 = (i2 < 1) ? 1 : ((i2 > NB - 1) ? NB - 1 : i2);
        float dxv = xp[i2] - xp[i2 - 1];
        float f;
        if (dxv == 0.0f) f = fp[i2];
        else f = fp[i2 - 1] + (x - xp[i2 - 1]) / dxv * (fp[i2] - fp[i2 - 1]);
        if (x < xp[0]) f = fp[0];

        float l = truncf(f);
        if (t == firstS) l = 0.0f;
        if (!((nOccS > 1) && (nOccR > 1))) l = 0.0f;

        lut[cb * NB + t] = l;
    }

    grid.sync();

    // ---------------- Phase 3: loss (only inp read; q/m from registers) ----
    llut[t] = lut[c * NB + t];
    __syncthreads();

    const float4* inpc = inp4 + (size_t)c * HW4;
    float s = 0.0f;
#pragma unroll
    for (int j = 0; j < NIT; ++j) {
        const int i = base0 + j * STRIDE;
        if (i < HW4) {
            const float4 X = inpc[i];
            const float xv[4] = {X.x, X.y, X.z, X.w};
#pragma unroll
            for (int k = 0; k < 4; ++k) {
                const int q = (qp[j] >> (8 * k)) & 255;
                const float mf = (float)((mbv >> (4 * j + k)) & 1u);
                const float im = (xv[k] + 1.0f) * 127.5f;
                s += mf * fabsf(im - llut[q]);
            }
        }
    }
#pragma unroll
    for (int off = 32; off > 0; off >>= 1) s += __shfl_down(s, off);
    if (lane == 0) wsum[wave] = s;
    __syncthreads();
    if (t == 0) lsum[cb] = wsum[0] + wsum[1] + wsum[2] + wsum[3];

    grid.sync();

    // ---------------- Phase 4: deterministic final reduce (block 0) --------
    if (cb == 0) {
        float ss = 0.0f;
        for (int i = t; i < NBLK; i += 256) ss += lsum[i];
#pragma unroll
        for (int off = 32; off > 0; off >>= 1) ss += __shfl_down(ss, off);
        if (lane == 0) wsum[wave] = ss;
        __syncthreads();
        if (t == 0) out[0] = (wsum[0] + wsum[1] + wsum[2] + wsum[3]) / (float)NTOT;
    }
}

extern "C" void kernel_launch(void* const* d_in, const int* in_sizes, int n_in,
                              void* d_out, int out_size, void* d_ws, size_t ws_size,
                              hipStream_t stream) {
    const float4* inp = (const float4*)d_in[0];
    const float4* tar = (const float4*)d_in[1];
    const float4* ref = (const float4*)d_in[2];
    const float4* ms  = (const float4*)d_in[3];
    const float4* mt  = (const float4*)d_in[4];

    char* ws = (char*)d_ws;
    int*   hsPart = (int*)(ws + WS_HSP_OFF);
    int*   hrPart = (int*)(ws + WS_HRP_OFF);
    float* lut    = (float*)(ws + WS_LUT_OFF);
    float* lsum   = (float*)(ws + WS_LSUM_OFF);
    float* outp   = (float*)d_out;

    void* args[] = {&inp, &tar, &ref, &ms, &mt,
                    &hsPart, &hrPart, &lut, &lsum, &outp};
    hipLaunchCooperativeKernel(reinterpret_cast<void*>(fused_kernel),
                               dim3(NBLK), dim3(256), args, 0, stream);
}

// Round 2
// 174.415 us; speedup vs baseline: 2.5448x; 2.5448x over previous
//
#include <hip/hip_runtime.h>

// Problem constants (from reference setup_inputs): B=8, C=3, H=W=512
#define HW    262144        // 512*512
#define HW4   65536         // HW/4 float4 elements per channel
#define BC    24            // B*C channels
#define NB    256           // bins
#define NTOT  6291456       // B*C*H*W

#define GH    64            // hist blocks per channel (4 float4/thread)
#define GL    64            // loss blocks per channel (4 float4/thread)
#define TOTL  (BC * GL)     // 1536 loss blocks

// Workspace layout (bytes) — nothing needs pre-zeroing (counter zeroed by k1):
//   [0, 1572864)            hsPart : int[24][GH][256]
//   [1572864, 3145728)      hrPart : int[24][GH][256]
//   [3145728, 15728640)     qm     : ushort[24][HW]   q | (mask<<8) per pixel
//   [15728640, 15734784)    lsum   : float[TOTL]
//   [15734784, 15734788)    counter: unsigned
#define WS_HSP_OFF  0
#define WS_HRP_OFF  1572864
#define WS_QM_OFF   3145728
#define WS_LSUM_OFF 15728640
#define WS_CNT_OFF  15734784

__device__ __forceinline__ int quantize(float x, float m) {
    // jnp.clip(jnp.round((x+1)*0.5*255 * m), 0, 255)
    float v = (x + 1.0f) * 0.5f * 255.0f * m;
    float r = rintf(v);
    r = fminf(fmaxf(r, 0.0f), 255.0f);
    return (int)r;
}

__device__ __forceinline__ int incl_scan256(int v, int t, int* buf) {
    buf[t] = v;
    __syncthreads();
#pragma unroll
    for (int off = 1; off < NB; off <<= 1) {
        int x = (t >= off) ? buf[t - off] : 0;
        __syncthreads();
        buf[t] += x;
        __syncthreads();
    }
    return buf[t];
}

// ---------------- Stage 1: per-channel partial histograms + qm store -------
// grid dim3(GH, 24), block 256. All 16 float4 loads issued before use.
// Emits packed q|(m<<8) per pixel so stage 2 never re-reads ref/ms.
__global__ void __launch_bounds__(256)
hist_kernel(const float4* __restrict__ ref4,
            const float4* __restrict__ tar4,
            const float4* __restrict__ ms4,
            const float4* __restrict__ mt4,
            int* __restrict__ hsPart, int* __restrict__ hrPart,
            ushort4* __restrict__ qm, unsigned* __restrict__ counter) {
    __shared__ int wh[4 * 2 * NB];        // [wave][s/r][bin]
    const int t = threadIdx.x;
    const int wave = t >> 6;
    const int lane = t & 63;

    if (blockIdx.x == 0 && blockIdx.y == 0 && t == 0) *counter = 0u;

#pragma unroll
    for (int j = 0; j < 8; ++j) wh[t + j * 256] = 0;
    __syncthreads();

    const int c = blockIdx.y;
    const int b = c / 3;
    const float4* refc = ref4 + (size_t)c * HW4;
    const float4* tarc = tar4 + (size_t)c * HW4;
    const float4* msb  = ms4 + (size_t)b * HW4;
    const float4* mtb  = mt4 + (size_t)b * HW4;
    ushort4* qmc = qm + (size_t)c * HW4;

    const int base = blockIdx.x * 256 + t;   // stride GH*256 = 16384

    // ---- load phase: 16 independent float4 loads in flight ----
    float4 R[4], T[4], M[4], MT[4];
#pragma unroll
    for (int j = 0; j < 4; ++j) R[j]  = refc[base + j * 16384];
#pragma unroll
    for (int j = 0; j < 4; ++j) M[j]  = msb[base + j * 16384];
#pragma unroll
    for (int j = 0; j < 4; ++j) T[j]  = tarc[base + j * 16384];
#pragma unroll
    for (int j = 0; j < 4; ++j) MT[j] = mtb[base + j * 16384];

    // ---- process phase ----
    int* whS = &wh[wave * 512];
    int* whR = &wh[wave * 512 + 256];
    int n0s = 0, n0r = 0;
#pragma unroll
    for (int j = 0; j < 4; ++j) {
        const float rv[4]  = {R[j].x, R[j].y, R[j].z, R[j].w};
        const float mv[4]  = {M[j].x, M[j].y, M[j].z, M[j].w};
        const float tvv[4] = {T[j].x, T[j].y, T[j].z, T[j].w};
        const float mtv[4] = {MT[j].x, MT[j].y, MT[j].z, MT[j].w};
        unsigned u16[4];
#pragma unroll
        for (int k = 0; k < 4; ++k) {
            const int qs = quantize(rv[k], mv[k]);   // 0 when mask==0
            const bool ms_on = (mv[k] != 0.0f);
            u16[k] = (unsigned)qs | (ms_on ? 256u : 0u);
            if (ms_on) atomicAdd(&whS[qs], 1);
            else n0s++;
            if (mtv[k] != 0.0f) atomicAdd(&whR[quantize(tvv[k], mtv[k])], 1);
            else n0r++;
        }
        ushort4 qq;
        qq.x = (unsigned short)u16[0];
        qq.y = (unsigned short)u16[1];
        qq.z = (unsigned short)u16[2];
        qq.w = (unsigned short)u16[3];
        qmc[base + j * 16384] = qq;
    }
    // fold register bin-0 counts: wave-reduce, one LDS add per wave
#pragma unroll
    for (int off = 32; off > 0; off >>= 1) {
        n0s += __shfl_down(n0s, off);
        n0r += __shfl_down(n0r, off);
    }
    if (lane == 0) {
        if (n0s) atomicAdd(&whS[0], n0s);
        if (n0r) atomicAdd(&whR[0], n0r);
    }
    __syncthreads();

    // merge 4 wave-hists -> per-block partial, plain coalesced store
    const int s = wh[t] + wh[512 + t] + wh[1024 + t] + wh[1536 + t];
    const int r = wh[256 + t] + wh[768 + t] + wh[1280 + t] + wh[1792 + t];
    hsPart[(c * GH + blockIdx.x) * NB + t] = s;
    hrPart[(c * GH + blockIdx.x) * NB + t] = r;
}

// ---------------- Stage 2: LUT (redundant per block) + loss + finalize -----
// grid dim3(GL, 24), block 256. Each block recomputes its channel's LUT from
// the partials (L2-resident) — no serial 24-block kernel, no launch gap.
// inp/qm loads issued first so HBM latency hides under the LUT scan.
__global__ void __launch_bounds__(256)
loss_kernel(const float4* __restrict__ inp4,
            const int* __restrict__ hsPart,
            const int* __restrict__ hrPart,
            const ushort4* __restrict__ qm,
            float* __restrict__ lsum,
            unsigned* __restrict__ counter,
            float* __restrict__ out) {
    __shared__ int   buf[NB];
    __shared__ float xp[NB];
    __shared__ float fp[NB];
    __shared__ float llut[NB];
    __shared__ float wsum[4];
    __shared__ int firstS, firstR, nOccS, nOccR, isLast;

    const int t = threadIdx.x;
    const int c = blockIdx.y;
    const int g = blockIdx.x;
    const int lane = t & 63;
    const int wave = t >> 6;

    // ---- issue loss-phase loads early (complete during LUT compute) ----
    const float4*  inpc = inp4 + (size_t)c * HW4;
    const ushort4* qmc  = qm + (size_t)c * HW4;
    const int base = g * 256 + t;            // stride GL*256 = 16384
    float4  X[4];
    ushort4 Q[4];
#pragma unroll
    for (int j = 0; j < 4; ++j) X[j] = inpc[base + j * 16384];
#pragma unroll
    for (int j = 0; j < 4; ++j) Q[j] = qmc[base + j * 16384];

    // ---- LUT phase (identical math to verified lut_kernel) ----
    int cs = 0, cr = 0;
#pragma unroll 4
    for (int gg = 0; gg < GH; ++gg) {
        cs += hsPart[(c * GH + gg) * NB + t];
        cr += hrPart[(c * GH + gg) * NB + t];
    }

    if (t == 0) { firstS = NB; firstR = NB; nOccS = 0; nOccR = 0; }
    __syncthreads();
    if (cs > 0) { atomicMin(&firstS, t); atomicAdd(&nOccS, 1); }
    if (cr > 0) { atomicMin(&firstR, t); atomicAdd(&nOccR, 1); }
    __syncthreads();

    const int csz = (t == firstS) ? 0 : cs;
    const int crz = (t == firstR) ? 0 : cr;

    const int cumS = incl_scan256(csz, t, buf);
    const int totS = buf[NB - 1];
    __syncthreads();
    const int cumR = incl_scan256(crz, t, buf);
    const int totR = buf[NB - 1];
    __syncthreads();
    const int occ2 = (cr > 0 && t != firstR) ? 1 : 0;
    const int rank = incl_scan256(occ2, t, buf) - occ2;  // exclusive
    __syncthreads();

    const float x  = (float)cumS / fmaxf((float)totS, 1.0f);
    const float rq = (float)cumR / fmaxf((float)totR, 1.0f);

    xp[t] = 2.0f;
    fp[t] = 0.0f;
    __syncthreads();
    if (occ2) { xp[rank] = rq; fp[rank] = (float)t; }
    __syncthreads();

    // jnp.interp semantics: searchsorted-right, i clipped to [1,255]
    int lo = 0, hi = NB;
    while (lo < hi) {
        int mid = (lo + hi) >> 1;
        if (xp[mid] > x) hi = mid; else lo = mid + 1;
    }
    int i2 = lo;
    i2 = (i2 < 1) ? 1 : ((i2 > NB - 1) ? NB - 1 : i2);
    float dxv = xp[i2] - xp[i2 - 1];
    float f;
    if (dxv == 0.0f) f = fp[i2];
    else f = fp[i2 - 1] + (x - xp[i2 - 1]) / dxv * (fp[i2] - fp[i2 - 1]);
    if (x < xp[0]) f = fp[0];

    float l = truncf(f);
    if (t == firstS) l = 0.0f;
    if (!((nOccS > 1) && (nOccR > 1))) l = 0.0f;

    llut[t] = l;
    __syncthreads();

    // ---- loss phase: q/m from packed qm, only inp from HBM ----
    float s = 0.0f;
#pragma unroll
    for (int j = 0; j < 4; ++j) {
        const float xv[4] = {X[j].x, X[j].y, X[j].z, X[j].w};
        const unsigned qv[4] = {Q[j].x, Q[j].y, Q[j].z, Q[j].w};
#pragma unroll
        for (int k = 0; k < 4; ++k) {
            const int q = (int)(qv[k] & 255u);
            const float mf = (float)((qv[k] >> 8) & 1u);
            const float im = (xv[k] + 1.0f) * 127.5f;
            s += mf * fabsf(im - llut[q]);
        }
    }

#pragma unroll
    for (int off = 32; off > 0; off >>= 1) s += __shfl_down(s, off);
    if (lane == 0) wsum[wave] = s;
    __syncthreads();
    if (t == 0) {
        lsum[c * GL + g] = wsum[0] + wsum[1] + wsum[2] + wsum[3];
        __threadfence();
        unsigned old = atomicAdd(counter, 1u);
        isLast = (old == (unsigned)(TOTL - 1)) ? 1 : 0;
    }
    __syncthreads();

    // ---- last block: deterministic final reduce (same order as before) ----
    if (isLast) {
        float ss = 0.0f;
#pragma unroll 2
        for (int i = t; i < TOTL; i += 256)
            ss += atomicAdd(&lsum[i], 0.0f);   // device-scope read (cross-XCD safe)
#pragma unroll
        for (int off = 32; off > 0; off >>= 1) ss += __shfl_down(ss, off);
        if (lane == 0) wsum[wave] = ss;
        __syncthreads();
        if (t == 0)
            out[0] = (wsum[0] + wsum[1] + wsum[2] + wsum[3]) / (float)NTOT;
    }
}

extern "C" void kernel_launch(void* const* d_in, const int* in_sizes, int n_in,
                              void* d_out, int out_size, void* d_ws, size_t ws_size,
                              hipStream_t stream) {
    const float* inp  = (const float*)d_in[0];
    const float* tar  = (const float*)d_in[1];
    const float* ref  = (const float*)d_in[2];
    const float* msrc = (const float*)d_in[3];
    const float* mtar = (const float*)d_in[4];

    char* ws = (char*)d_ws;
    int*      hsPart  = (int*)(ws + WS_HSP_OFF);
    int*      hrPart  = (int*)(ws + WS_HRP_OFF);
    ushort4*  qm      = (ushort4*)(ws + WS_QM_OFF);
    float*    lsum    = (float*)(ws + WS_LSUM_OFF);
    unsigned* counter = (unsigned*)(ws + WS_CNT_OFF);

    hist_kernel<<<dim3(GH, BC), 256, 0, stream>>>(
        (const float4*)ref, (const float4*)tar,
        (const float4*)msrc, (const float4*)mtar,
        hsPart, hrPart, qm, counter);

    loss_kernel<<<dim3(GL, BC), 256, 0, stream>>>(
        (const float4*)inp, hsPart, hrPart, qm, lsum, counter, (float*)d_out);
}

// Round 3
// 154.725 us; speedup vs baseline: 2.8686x; 1.1273x over previous
//
#include <hip/hip_runtime.h>

// Problem constants (from reference setup_inputs): B=8, C=3, H=W=512
#define HW    262144        // 512*512
#define HW4   65536         // HW/4 float4 elements per channel
#define BC    24            // B*C channels
#define NB    256           // bins
#define NTOT  6291456       // B*C*H*W

#define GH    64            // hist blocks per channel (4 float4/thread)
#define GL    64            // loss blocks per channel (4 float4/thread)
#define TOTL  (BC * GL)     // 1536 loss blocks

// Workspace layout (bytes):
//   [0, 24576)              histS : int[24][256]   (memset to 0 each launch)
//   [24576, 49152)          histR : int[24][256]   (memset to 0 each launch)
//   [49152, 12632064)       qm    : ushort[24][HW]  q | (mask<<8) per pixel
//   [12632064, 12638208)    lsum  : float[TOTL]
//   [12638208, 12638212)    counter: unsigned       (zeroed inside hist_kernel)
#define WS_HS_OFF   0
#define WS_HR_OFF   24576
#define WS_QM_OFF   49152
#define WS_LSUM_OFF 12632064
#define WS_CNT_OFF  12638208

__device__ __forceinline__ int quantize(float x, float m) {
    // jnp.clip(jnp.round((x+1)*0.5*255 * m), 0, 255)
    float v = (x + 1.0f) * 0.5f * 255.0f * m;
    float r = rintf(v);
    r = fminf(fmaxf(r, 0.0f), 255.0f);
    return (int)r;
}

__device__ __forceinline__ int incl_scan256(int v, int t, int* buf) {
    buf[t] = v;
    __syncthreads();
#pragma unroll
    for (int off = 1; off < NB; off <<= 1) {
        int x = (t >= off) ? buf[t - off] : 0;
        __syncthreads();
        buf[t] += x;
        __syncthreads();
    }
    return buf[t];
}

// ---------------- Stage 1: per-channel histograms (global-atomic merge) ----
// grid dim3(GH, 24), block 256. All 16 float4 loads issued before use.
// Emits packed q|(m<<8) per pixel so stage 2 never re-reads ref/ms.
// Block-merged hist folded into final int hist[24][256] via device atomics
// (integer adds: order-independent -> deterministic).
__global__ void __launch_bounds__(256)
hist_kernel(const float4* __restrict__ ref4,
            const float4* __restrict__ tar4,
            const float4* __restrict__ ms4,
            const float4* __restrict__ mt4,
            int* __restrict__ histS, int* __restrict__ histR,
            ushort4* __restrict__ qm, unsigned* __restrict__ counter) {
    __shared__ int wh[4 * 2 * NB];        // [wave][s/r][bin]
    const int t = threadIdx.x;
    const int wave = t >> 6;
    const int lane = t & 63;

    if (blockIdx.x == 0 && blockIdx.y == 0 && t == 0) *counter = 0u;

#pragma unroll
    for (int j = 0; j < 8; ++j) wh[t + j * 256] = 0;
    __syncthreads();

    const int c = blockIdx.y;
    const int b = c / 3;
    const float4* refc = ref4 + (size_t)c * HW4;
    const float4* tarc = tar4 + (size_t)c * HW4;
    const float4* msb  = ms4 + (size_t)b * HW4;
    const float4* mtb  = mt4 + (size_t)b * HW4;
    ushort4* qmc = qm + (size_t)c * HW4;

    const int base = blockIdx.x * 256 + t;   // stride GH*256 = 16384

    // ---- load phase: 16 independent float4 loads in flight ----
    float4 R[4], T[4], M[4], MT[4];
#pragma unroll
    for (int j = 0; j < 4; ++j) R[j]  = refc[base + j * 16384];
#pragma unroll
    for (int j = 0; j < 4; ++j) M[j]  = msb[base + j * 16384];
#pragma unroll
    for (int j = 0; j < 4; ++j) T[j]  = tarc[base + j * 16384];
#pragma unroll
    for (int j = 0; j < 4; ++j) MT[j] = mtb[base + j * 16384];

    // ---- process phase ----
    int* whS = &wh[wave * 512];
    int* whR = &wh[wave * 512 + 256];
    int n0s = 0, n0r = 0;
#pragma unroll
    for (int j = 0; j < 4; ++j) {
        const float rv[4]  = {R[j].x, R[j].y, R[j].z, R[j].w};
        const float mv[4]  = {M[j].x, M[j].y, M[j].z, M[j].w};
        const float tvv[4] = {T[j].x, T[j].y, T[j].z, T[j].w};
        const float mtv[4] = {MT[j].x, MT[j].y, MT[j].z, MT[j].w};
        unsigned u16[4];
#pragma unroll
        for (int k = 0; k < 4; ++k) {
            const int qs = quantize(rv[k], mv[k]);   // 0 when mask==0
            const bool ms_on = (mv[k] != 0.0f);
            u16[k] = (unsigned)qs | (ms_on ? 256u : 0u);
            if (ms_on) atomicAdd(&whS[qs], 1);
            else n0s++;
            if (mtv[k] != 0.0f) atomicAdd(&whR[quantize(tvv[k], mtv[k])], 1);
            else n0r++;
        }
        ushort4 qq;
        qq.x = (unsigned short)u16[0];
        qq.y = (unsigned short)u16[1];
        qq.z = (unsigned short)u16[2];
        qq.w = (unsigned short)u16[3];
        qmc[base + j * 16384] = qq;
    }
    // fold register bin-0 counts: wave-reduce, one LDS add per wave
#pragma unroll
    for (int off = 32; off > 0; off >>= 1) {
        n0s += __shfl_down(n0s, off);
        n0r += __shfl_down(n0r, off);
    }
    if (lane == 0) {
        if (n0s) atomicAdd(&whS[0], n0s);
        if (n0r) atomicAdd(&whR[0], n0r);
    }
    __syncthreads();

    // merge 4 wave-hists -> device-scope atomic add into final channel hist
    const int s = wh[t] + wh[512 + t] + wh[1024 + t] + wh[1536 + t];
    const int r = wh[256 + t] + wh[768 + t] + wh[1280 + t] + wh[1792 + t];
    if (s) atomicAdd(&histS[c * NB + t], s);
    if (r) atomicAdd(&histR[c * NB + t], r);
}

// ---------------- Stage 2: LUT (redundant, cheap input) + loss + finalize --
// grid dim3(GL, 24), block 256. Each block recomputes its channel's LUT from
// the FINAL histogram (2 KB/block, L2/L3-broadcast) — 65x less read traffic
// than the partials version. inp/qm loads issued first so HBM latency hides
// under the LUT scan.
__global__ void __launch_bounds__(256)
loss_kernel(const float4* __restrict__ inp4,
            const int* __restrict__ histS,
            const int* __restrict__ histR,
            const ushort4* __restrict__ qm,
            float* __restrict__ lsum,
            unsigned* __restrict__ counter,
            float* __restrict__ out) {
    __shared__ int   buf[NB];
    __shared__ float xp[NB];
    __shared__ float fp[NB];
    __shared__ float llut[NB];
    __shared__ float wsum[4];
    __shared__ int firstS, firstR, nOccS, nOccR, isLast;

    const int t = threadIdx.x;
    const int c = blockIdx.y;
    const int g = blockIdx.x;
    const int lane = t & 63;
    const int wave = t >> 6;

    // ---- issue loss-phase loads early (complete during LUT compute) ----
    const float4*  inpc = inp4 + (size_t)c * HW4;
    const ushort4* qmc  = qm + (size_t)c * HW4;
    const int base = g * 256 + t;            // stride GL*256 = 16384
    float4  X[4];
    ushort4 Q[4];
#pragma unroll
    for (int j = 0; j < 4; ++j) X[j] = inpc[base + j * 16384];
#pragma unroll
    for (int j = 0; j < 4; ++j) Q[j] = qmc[base + j * 16384];

    // ---- LUT phase (identical math to verified lut_kernel) ----
    const int cs = histS[c * NB + t];
    const int cr = histR[c * NB + t];

    if (t == 0) { firstS = NB; firstR = NB; nOccS = 0; nOccR = 0; }
    __syncthreads();
    if (cs > 0) { atomicMin(&firstS, t); atomicAdd(&nOccS, 1); }
    if (cr > 0) { atomicMin(&firstR, t); atomicAdd(&nOccR, 1); }
    __syncthreads();

    const int csz = (t == firstS) ? 0 : cs;
    const int crz = (t == firstR) ? 0 : cr;

    const int cumS = incl_scan256(csz, t, buf);
    const int totS = buf[NB - 1];
    __syncthreads();
    const int cumR = incl_scan256(crz, t, buf);
    const int totR = buf[NB - 1];
    __syncthreads();
    const int occ2 = (cr > 0 && t != firstR) ? 1 : 0;
    const int rank = incl_scan256(occ2, t, buf) - occ2;  // exclusive
    __syncthreads();

    const float x  = (float)cumS / fmaxf((float)totS, 1.0f);
    const float rq = (float)cumR / fmaxf((float)totR, 1.0f);

    xp[t] = 2.0f;
    fp[t] = 0.0f;
    __syncthreads();
    if (occ2) { xp[rank] = rq; fp[rank] = (float)t; }
    __syncthreads();

    // jnp.interp semantics: searchsorted-right, i clipped to [1,255]
    int lo = 0, hi = NB;
    while (lo < hi) {
        int mid = (lo + hi) >> 1;
        if (xp[mid] > x) hi = mid; else lo = mid + 1;
    }
    int i2 = lo;
    i2 = (i2 < 1) ? 1 : ((i2 > NB - 1) ? NB - 1 : i2);
    float dxv = xp[i2] - xp[i2 - 1];
    float f;
    if (dxv == 0.0f) f = fp[i2];
    else f = fp[i2 - 1] + (x - xp[i2 - 1]) / dxv * (fp[i2] - fp[i2 - 1]);
    if (x < xp[0]) f = fp[0];

    float l = truncf(f);
    if (t == firstS) l = 0.0f;
    if (!((nOccS > 1) && (nOccR > 1))) l = 0.0f;

    llut[t] = l;
    __syncthreads();

    // ---- loss phase: q/m from packed qm, only inp from HBM ----
    float s = 0.0f;
#pragma unroll
    for (int j = 0; j < 4; ++j) {
        const float xv[4] = {X[j].x, X[j].y, X[j].z, X[j].w};
        const unsigned qv[4] = {Q[j].x, Q[j].y, Q[j].z, Q[j].w};
#pragma unroll
        for (int k = 0; k < 4; ++k) {
            const int q = (int)(qv[k] & 255u);
            const float mf = (float)((qv[k] >> 8) & 1u);
            const float im = (xv[k] + 1.0f) * 127.5f;
            s += mf * fabsf(im - llut[q]);
        }
    }

#pragma unroll
    for (int off = 32; off > 0; off >>= 1) s += __shfl_down(s, off);
    if (lane == 0) wsum[wave] = s;
    __syncthreads();
    if (t == 0) {
        lsum[c * GL + g] = wsum[0] + wsum[1] + wsum[2] + wsum[3];
        __threadfence();
        unsigned old = atomicAdd(counter, 1u);
        isLast = (old == (unsigned)(TOTL - 1)) ? 1 : 0;
    }
    __syncthreads();

    // ---- last block: deterministic final reduce (same order as before) ----
    if (isLast) {
        float ss = 0.0f;
#pragma unroll 2
        for (int i = t; i < TOTL; i += 256)
            ss += atomicAdd(&lsum[i], 0.0f);   // device-scope read (cross-XCD safe)
#pragma unroll
        for (int off = 32; off > 0; off >>= 1) ss += __shfl_down(ss, off);
        if (lane == 0) wsum[wave] = ss;
        __syncthreads();
        if (t == 0)
            out[0] = (wsum[0] + wsum[1] + wsum[2] + wsum[3]) / (float)NTOT;
    }
}

extern "C" void kernel_launch(void* const* d_in, const int* in_sizes, int n_in,
                              void* d_out, int out_size, void* d_ws, size_t ws_size,
                              hipStream_t stream) {
    const float* inp  = (const float*)d_in[0];
    const float* tar  = (const float*)d_in[1];
    const float* ref  = (const float*)d_in[2];
    const float* msrc = (const float*)d_in[3];
    const float* mtar = (const float*)d_in[4];

    char* ws = (char*)d_ws;
    int*      histS   = (int*)(ws + WS_HS_OFF);
    int*      histR   = (int*)(ws + WS_HR_OFF);
    ushort4*  qm      = (ushort4*)(ws + WS_QM_OFF);
    float*    lsum    = (float*)(ws + WS_LSUM_OFF);
    unsigned* counter = (unsigned*)(ws + WS_CNT_OFF);

    // hist bins must start at 0 under workspace re-poison (48 KB, ~µs).
    hipMemsetAsync(ws + WS_HS_OFF, 0, 2 * BC * NB * sizeof(int), stream);

    hist_kernel<<<dim3(GH, BC), 256, 0, stream>>>(
        (const float4*)ref, (const float4*)tar,
        (const float4*)msrc, (const float4*)mtar,
        histS, histR, qm, counter);

    loss_kernel<<<dim3(GL, BC), 256, 0, stream>>>(
        (const float4*)inp, histS, histR, qm, lsum, counter, (float*)d_out);
}